// Round 10
// baseline (896.284 us; speedup 1.0000x reference)
//
#include <hip/hip_runtime.h>

#define NN 263
#define TT 24

typedef __fp16 h2 __attribute__((ext_vector_type(2)));
typedef _Float16 f16x4 __attribute__((ext_vector_type(4)));
typedef _Float16 f16x8 __attribute__((ext_vector_type(8)));
typedef float f32x4 __attribute__((ext_vector_type(4)));

struct WSegs  { const float* p[6]; };      // fp32 weight tiles (legacy gemm)
struct WSegsH { const _Float16* p[6]; };   // f16 weight tiles
struct CvtSegs { const float* src[11]; _Float16* dst[11]; int cnt8[11]; };

static __device__ __forceinline__ float wred_sum(float v) {
  #pragma unroll
  for (int off = 32; off >= 1; off >>= 1) v += __shfl_xor(v, off, 64);
  return v;
}
static __device__ __forceinline__ float wred_max(float v) {
  #pragma unroll
  for (int off = 32; off >= 1; off >>= 1) v = fmaxf(v, __shfl_xor(v, off, 64));
  return v;
}

// ---------------------------------------------------------------------------
// Batched fp32 -> f16 convert (x + all weights), 8 elems/thread-iter.
// ---------------------------------------------------------------------------
__global__ __launch_bounds__(256) void cvt_f16(CvtSegs cs, int nseg, int total8)
{
  const int stride = gridDim.x * 256;
  for (int i = blockIdx.x * 256 + threadIdx.x; i < total8; i += stride) {
    int r = i, s = 0;
    while (s < nseg - 1 && r >= cs.cnt8[s]) { r -= cs.cnt8[s]; ++s; }
    const float* sp = cs.src[s] + (size_t)r * 8;
    float4 a = *(const float4*)sp;
    float4 b = *(const float4*)(sp + 4);
    union { h2 h[4]; f16x8 v; } u;
    u.h[0] = __builtin_amdgcn_cvt_pkrtz(a.x, a.y);
    u.h[1] = __builtin_amdgcn_cvt_pkrtz(a.z, a.w);
    u.h[2] = __builtin_amdgcn_cvt_pkrtz(b.x, b.y);
    u.h[3] = __builtin_amdgcn_cvt_pkrtz(b.z, b.w);
    *(f16x8*)(cs.dst[s] + (size_t)r * 8) = u.v;
  }
}

// ---------------------------------------------------------------------------
// f16-in MFMA NT GEMM (verified R6-R9): dbuf LDS, one barrier/K-step.
// R9: OUT_HALF=1 epilogue stages the C-tile through LDS and writes 256B
// contiguous f16 rows — the old 16-lane scalar f16 stores were 32B partial
// sectors -> read-modify-write amplification (~3x WRITE, big FETCH).
// ---------------------------------------------------------------------------
template<int OUT_HALF>
__global__ __launch_bounds__(256) void gemm_h16(
    const _Float16* __restrict__ A, WSegsH wsg, const float* __restrict__ bias,
    void* __restrict__ Cp, int M, int NT, int K, int ldc)
{
  __shared__ _Float16 As[2][128][40];
  __shared__ _Float16 Bs[2][128][40];
  const int tid  = threadIdx.x;
  const int lane = tid & 63;
  const int wave = tid >> 6;
  const int wr = wave >> 1, wc = wave & 1;

  const int nwg = gridDim.x;
  const int q8 = nwg >> 3, r8 = nwg & 7;
  const int xcd = blockIdx.x & 7, pos = blockIdx.x >> 3;
  const int logical = (xcd < r8 ? xcd * (q8 + 1) : r8 * (q8 + 1) + (xcd - r8) * q8) + pos;
  const int bm = (logical / NT) * 128;
  const int bn = logical - (logical / NT) * NT;
  const _Float16* __restrict__ W = wsg.p[bn];

  const int srow = tid >> 2;
  const int sch  = (tid & 3) * 8;
  const _Float16* aptr[2];
  const _Float16* bptr[2];
  #pragma unroll
  for (int l = 0; l < 2; ++l) {
    int gm = bm + srow + 64 * l; if (gm > M - 1) gm = M - 1;
    aptr[l] = A + (size_t)gm * K + sch;
    bptr[l] = W + (size_t)(srow + 64 * l) * K + sch;
  }

  f32x4 acc[4][4];
  #pragma unroll
  for (int i = 0; i < 4; ++i)
    #pragma unroll
    for (int j = 0; j < 4; ++j) {
      acc[i][j].x = 0.f; acc[i][j].y = 0.f; acc[i][j].z = 0.f; acc[i][j].w = 0.f;
    }

  const int fr = lane & 15;
  const int fk = (lane >> 4) * 8;

  f16x8 av[2], bv[2];
  av[0] = *(const f16x8*)aptr[0]; av[1] = *(const f16x8*)aptr[1];
  bv[0] = *(const f16x8*)bptr[0]; bv[1] = *(const f16x8*)bptr[1];

  int cur = 0;
  for (int k0 = 0; k0 < K; k0 += 32, cur ^= 1) {
    *(f16x8*)&As[cur][srow     ][sch] = av[0];
    *(f16x8*)&As[cur][srow + 64][sch] = av[1];
    *(f16x8*)&Bs[cur][srow     ][sch] = bv[0];
    *(f16x8*)&Bs[cur][srow + 64][sch] = bv[1];
    if (k0 + 32 < K) {
      av[0] = *(const f16x8*)(aptr[0] + k0 + 32);
      av[1] = *(const f16x8*)(aptr[1] + k0 + 32);
      bv[0] = *(const f16x8*)(bptr[0] + k0 + 32);
      bv[1] = *(const f16x8*)(bptr[1] + k0 + 32);
    }
    __syncthreads();

    f16x8 af[4], bf[4];
    #pragma unroll
    for (int mi = 0; mi < 4; ++mi)
      af[mi] = *(const f16x8*)&As[cur][wr * 64 + mi * 16 + fr][fk];
    #pragma unroll
    for (int ni = 0; ni < 4; ++ni)
      bf[ni] = *(const f16x8*)&Bs[cur][wc * 64 + ni * 16 + fr][fk];
    #pragma unroll
    for (int mi = 0; mi < 4; ++mi)
      #pragma unroll
      for (int ni = 0; ni < 4; ++ni)
        acc[mi][ni] = __builtin_amdgcn_mfma_f32_16x16x32_f16(
            af[mi], bf[ni], acc[mi][ni], 0, 0, 0);
  }

  if (OUT_HALF) {
    // LDS-staged f16 epilogue: two 64-row halves through As (dead after loop).
    // Row stride 136 f16 (16B-aligned, bank-rotating).
    _Float16* Cst = (_Float16*)As;   // 64 x 136 f16 = 17408 B <= 20480 B
    #pragma unroll
    for (int p = 0; p < 2; ++p) {
      __syncthreads();
      if (wr == p) {
        #pragma unroll
        for (int mi = 0; mi < 4; ++mi) {
          int lr = mi * 16 + (lane >> 4) * 4;
          #pragma unroll
          for (int r = 0; r < 4; ++r)
            #pragma unroll
            for (int ni = 0; ni < 4; ++ni) {
              float v = acc[mi][ni][r];
              if (bias) v += bias[bn * 128 + wc * 64 + ni * 16 + fr];
              Cst[(lr + r) * 136 + wc * 64 + ni * 16 + fr] = (_Float16)v;
            }
        }
      }
      __syncthreads();
      for (int it = tid; it < 64 * 16; it += 256) {
        int lr = it >> 4, ch = (it & 15) * 8;
        int gm = bm + p * 64 + lr;
        if (gm < M)
          *(f16x8*)((_Float16*)Cp + (size_t)gm * ldc + bn * 128 + ch) =
              *(const f16x8*)&Cst[lr * 136 + ch];
      }
    }
  } else {
    #pragma unroll
    for (int mi = 0; mi < 4; ++mi) {
      int rb = bm + wr * 64 + mi * 16 + (lane >> 4) * 4;
      #pragma unroll
      for (int r = 0; r < 4; ++r) {
        int gm = rb + r;
        if (gm < M) {
          int gn = bn * 128 + wc * 64 + fr;
          #pragma unroll
          for (int ni = 0; ni < 4; ++ni) {
            float v = acc[mi][ni][r];
            if (bias) v += bias[gn + ni * 16];
            ((float*)Cp)[(size_t)gm * ldc + gn + ni * 16] = v;
          }
        }
      }
    }
  }
}

// ---------------------------------------------------------------------------
// Legacy fp32-in GEMM — small agg projections only.
// ---------------------------------------------------------------------------
__global__ __launch_bounds__(256) void gemm_nt_mfma(
    const float* __restrict__ A, WSegs ws, const float* __restrict__ bias,
    float* __restrict__ C, int M, int NT, int K, int ldc)
{
  __shared__ _Float16 As[128][40];
  __shared__ _Float16 Bs[128][40];
  const int tid  = threadIdx.x;
  const int lane = tid & 63;
  const int wave = tid >> 6;
  const int wr = wave >> 1, wc = wave & 1;

  const int nwg = gridDim.x;
  const int q8 = nwg >> 3, r8 = nwg & 7;
  const int xcd = blockIdx.x & 7, pos = blockIdx.x >> 3;
  const int logical = (xcd < r8 ? xcd * (q8 + 1) : r8 * (q8 + 1) + (xcd - r8) * q8) + pos;
  const int bm = (logical / NT) * 128;
  const int bn = logical - (logical / NT) * NT;
  const float* __restrict__ W = ws.p[bn];

  const int srow = tid >> 3;
  const int skq  = (tid & 7) * 4;
  const float* aptr[4];
  const float* bptr[4];
  #pragma unroll
  for (int l = 0; l < 4; ++l) {
    int gm = bm + srow + 32 * l; if (gm > M - 1) gm = M - 1;
    aptr[l] = A + (size_t)gm * K + skq;
    bptr[l] = W + (size_t)(srow + 32 * l) * K + skq;
  }

  f32x4 acc[4][4];
  #pragma unroll
  for (int i = 0; i < 4; ++i)
    #pragma unroll
    for (int j = 0; j < 4; ++j) {
      acc[i][j].x = 0.f; acc[i][j].y = 0.f; acc[i][j].z = 0.f; acc[i][j].w = 0.f;
    }

  const int fr = lane & 15;
  const int fk = (lane >> 4) * 8;

  float4 av[4], bv[4];
  #pragma unroll
  for (int l = 0; l < 4; ++l) {
    av[l] = *(const float4*)(aptr[l]);
    bv[l] = *(const float4*)(bptr[l]);
  }

  for (int k0 = 0; k0 < K; k0 += 32) {
    #pragma unroll
    for (int l = 0; l < 4; ++l) {
      f16x4 a4, b4;
      a4.x = (_Float16)av[l].x; a4.y = (_Float16)av[l].y;
      a4.z = (_Float16)av[l].z; a4.w = (_Float16)av[l].w;
      b4.x = (_Float16)bv[l].x; b4.y = (_Float16)bv[l].y;
      b4.z = (_Float16)bv[l].z; b4.w = (_Float16)bv[l].w;
      *(f16x4*)&As[srow + 32 * l][skq] = a4;
      *(f16x4*)&Bs[srow + 32 * l][skq] = b4;
    }
    __syncthreads();

    if (k0 + 32 < K) {
      #pragma unroll
      for (int l = 0; l < 4; ++l) {
        av[l] = *(const float4*)(aptr[l] + k0 + 32);
        bv[l] = *(const float4*)(bptr[l] + k0 + 32);
      }
    }

    f16x8 af[4], bf[4];
    #pragma unroll
    for (int mi = 0; mi < 4; ++mi)
      af[mi] = *(const f16x8*)&As[wr * 64 + mi * 16 + fr][fk];
    #pragma unroll
    for (int ni = 0; ni < 4; ++ni)
      bf[ni] = *(const f16x8*)&Bs[wc * 64 + ni * 16 + fr][fk];
    #pragma unroll
    for (int mi = 0; mi < 4; ++mi)
      #pragma unroll
      for (int ni = 0; ni < 4; ++ni)
        acc[mi][ni] = __builtin_amdgcn_mfma_f32_16x16x32_f16(
            af[mi], bf[ni], acc[mi][ni], 0, 0, 0);
    __syncthreads();
  }

  #pragma unroll
  for (int mi = 0; mi < 4; ++mi) {
    int rb = bm + wr * 64 + mi * 16 + (lane >> 4) * 4;
    #pragma unroll
    for (int r = 0; r < 4; ++r) {
      int gm = rb + r;
      if (gm < M) {
        int gn = bn * 128 + wc * 64 + fr;
        float* crow = C + (size_t)gm * ldc + gn;
        #pragma unroll
        for (int ni = 0; ni < 4; ++ni) {
          float v = acc[mi][ni][r];
          if (bias) v += bias[gn + ni * 16];
          crow[ni * 16] = v;
        }
      }
    }
  }
}

// ---------------------------------------------------------------------------
__global__ void lam_kernel(const float* __restrict__ lq1, const float* __restrict__ lk1,
                           const float* __restrict__ lq2, const float* __restrict__ lk2,
                           float* __restrict__ out) {
  int lane = threadIdx.x;
  float v1 = lane < 32 ? lq1[lane] * lk1[lane] : 0.f;
  float v2 = lane < 32 ? lq2[lane] * lk2[lane] : 0.f;
  v1 = wred_sum(v1);
  v2 = wred_sum(v2);
  if (lane == 0) out[0] = expf(v1) - expf(v2) + 0.2f;
}

// ---------------------------------------------------------------------------
// Differential self-attention, MFMA (R9: output staged through per-wave Pb
// LDS then written as f16x8 full 128B lines — the scalar 2B stores were 32B
// partial sectors causing ~4x RMW fetch + 3x write amplification).
// ---------------------------------------------------------------------------
__global__ __launch_bounds__(512, 2) void diff_attn(
    const _Float16* __restrict__ qkv, _Float16* __restrict__ aout)
{
  __shared__ _Float16 Ks[2][272][40];   // [half][k-row][d(32)+pad8]
  __shared__ h2 Vt[64][148];            // Vt[d][kp] = (V[2kp][d], V[2kp+1][d])
  __shared__ h2 Pb[8][16][148];         // per-wave P: [qrow(16)][kp], pad zeroed

  const int h  = blockIdx.x & 3;
  const int bt = blockIdx.x >> 2;
  const int tid = threadIdx.x;
  const int lane = tid & 63;
  const int wave = tid >> 6;
  const int fr = lane & 15;
  const int kb = (lane >> 4) * 4;
  const _Float16* base = qkv + (size_t)bt * NN * 768;

  // ---- K staging: direct f16 16B copies ----
  for (int idx = tid; idx < 272 * 8; idx += 512) {
    int row = idx >> 3, c = idx & 7;
    int sr = row < NN ? row : NN - 1;
    f16x8 kv = *(const f16x8*)(base + (size_t)sr * 768 + 256 + h * 64 + c * 8);
    *(f16x8*)&Ks[c >> 2][row][(c & 3) * 8] = kv;
  }
  // ---- V staging: thread owns (d, 4 consecutive kp) -> one b128 write ----
  {
    const ushort* vb = (const ushort*)(base + 512 + h * 64);
    for (int idx = tid; idx < 64 * 37; idx += 512) {
      int d = idx & 63, kp0 = (idx >> 6) * 4;
      union { ushort u[8]; f16x8 v; } w;
      #pragma unroll
      for (int i = 0; i < 4; ++i) {
        int kp = kp0 + i;
        ushort lo = 0, hi = 0;
        if (kp < 136) {
          int m0 = 2 * kp, m1 = 2 * kp + 1;
          if (m0 > NN - 1) m0 = NN - 1;
          if (m1 > NN - 1) m1 = NN - 1;
          lo = vb[(size_t)m0 * 768 + d];
          hi = vb[(size_t)m1 * 768 + d];
        }
        w.u[2 * i] = lo; w.u[2 * i + 1] = hi;
      }
      *(f16x8*)&Vt[d][kp0] = w.v;
    }
  }
  // zero this wave's P pad columns kp=136..147
  {
    h2 z; z.x = (__fp16)0.f; z.y = (__fp16)0.f;
    #pragma unroll
    for (int t = 0; t < 3; ++t) Pb[wave][fr][136 + (kb >> 2) * 3 + t] = z;
  }
  __syncthreads();

  const float scq = 0.17677669529663687f;  // 1/sqrt(32)

  for (int task = wave; task < 34; task += 8) {
    const int chunk = task >> 1;
    const int half  = task & 1;

    int qsrc = chunk * 16 + fr; if (qsrc > NN - 1) qsrc = NN - 1;
    f16x8 qf = *(const f16x8*)(base + (size_t)qsrc * 768 + h * 64 + half * 32 + kb * 2);

    f32x4 s[17];
    #pragma unroll
    for (int mt = 0; mt < 17; ++mt) {
      f16x8 af = *(const f16x8*)&Ks[half][mt * 16 + fr][kb * 2];
      f32x4 z4 = {0.f, 0.f, 0.f, 0.f};
      s[mt] = __builtin_amdgcn_mfma_f32_16x16x32_f16(af, qf, z4, 0, 0, 0);
    }

    // softmax: 4 independent max/sum chains (depth 17), then 2 shfl each
    float mx4[4] = {-1e30f, -1e30f, -1e30f, -1e30f};
    #pragma unroll
    for (int mt = 0; mt < 17; ++mt)
      #pragma unroll
      for (int r = 0; r < 4; ++r) {
        float v = s[mt][r] * scq;
        if (mt * 16 + kb + r >= NN) v = -1e30f;
        s[mt][r] = v;
        mx4[r] = fmaxf(mx4[r], v);
      }
    float mx = fmaxf(fmaxf(mx4[0], mx4[1]), fmaxf(mx4[2], mx4[3]));
    mx = fmaxf(mx, __shfl_xor(mx, 16, 64));
    mx = fmaxf(mx, __shfl_xor(mx, 32, 64));
    float sm4[4] = {0.f, 0.f, 0.f, 0.f};
    #pragma unroll
    for (int mt = 0; mt < 17; ++mt)
      #pragma unroll
      for (int r = 0; r < 4; ++r) {
        float p = __expf(s[mt][r] - mx);
        s[mt][r] = p;
        sm4[r] += p;
      }
    float sum = (sm4[0] + sm4[1]) + (sm4[2] + sm4[3]);
    sum += __shfl_xor(sum, 16, 64);
    sum += __shfl_xor(sum, 32, 64);
    float inv = 1.f / sum;

    // write P as one b64 per mt: kp = 8*mt + (kb>>1)
    #pragma unroll
    for (int mt = 0; mt < 17; ++mt) {
      union { h2 h[2]; f16x4 v; } pw;
      pw.h[0] = __builtin_amdgcn_cvt_pkrtz(s[mt][0] * inv, s[mt][1] * inv);
      pw.h[1] = __builtin_amdgcn_cvt_pkrtz(s[mt][2] * inv, s[mt][3] * inv);
      *(f16x4*)&Pb[wave][fr][8 * mt + (kb >> 1)] = pw.v;
    }

    // PV: 9 K-steps of 32 (k padded to 288 with zero P / zero V)
    f32x4 o[4];
    #pragma unroll
    for (int nt = 0; nt < 4; ++nt) {
      o[nt].x = 0.f; o[nt].y = 0.f; o[nt].z = 0.f; o[nt].w = 0.f;
    }
    #pragma unroll
    for (int s9 = 0; s9 < 9; ++s9) {
      f16x8 pa = *(const f16x8*)&Pb[wave][fr][16 * s9 + kb];
      #pragma unroll
      for (int nt = 0; nt < 4; ++nt) {
        f16x8 vb2 = *(const f16x8*)&Vt[nt * 16 + fr][16 * s9 + kb];
        o[nt] = __builtin_amdgcn_mfma_f32_16x16x32_f16(pa, vb2, o[nt], 0, 0, 0);
      }
    }

    // ---- output: stage wave tile (16x64 f16) in Pb[wave] f16-cols 0..63
    // (pad cols 272..295 untouched), then 2 coalesced f16x8 instructions
    // writing 8 full 128B lines each ----
    _Float16* Ost = (_Float16*)&Pb[wave][0][0];   // row stride 296 f16
    #pragma unroll
    for (int r = 0; r < 4; ++r)
      #pragma unroll
      for (int nt = 0; nt < 4; ++nt)
        Ost[(kb + r) * 296 + nt * 16 + fr] = (_Float16)o[nt][r];

    _Float16* ab = aout + (size_t)half * (50496ull * 256ull);
    const int qbase = chunk * 16;
    #pragma unroll
    for (int g = 0; g < 2; ++g) {
      int ql = g * 8 + (lane >> 3);
      int ch = (lane & 7) * 8;
      int qrow = qbase + ql;
      f16x8 v = *(const f16x8*)&Ost[ql * 296 + ch];
      if (qrow < NN)
        *(f16x8*)(ab + ((size_t)(bt * NN + qrow) * 4 + h) * 64 + ch) = v;
    }
  }
}

// ---------------------------------------------------------------------------
// diff-LN: f16 in (a1/a2), f16 out (st_h).
// ---------------------------------------------------------------------------
__global__ __launch_bounds__(256) void diff_ln(
    const _Float16* __restrict__ a1, const _Float16* __restrict__ a2,
    const float* __restrict__ lamp,
    const float* __restrict__ g, const float* __restrict__ b,
    _Float16* __restrict__ st)
{
  const int btn = blockIdx.x;
  const int lane = threadIdx.x & 63;
  const int h = threadIdx.x >> 6;
  const float lam = lamp[0];
  size_t off = ((size_t)btn * 4 + h) * 64 + lane;
  float y = (float)a1[off] - lam * (float)a2[off];
  float mean = wred_sum(y) * (1.f / 64.f);
  float t = y - mean;
  float var = wred_sum(t * t) * (1.f / 64.f);
  float r = rsqrtf(var + 1e-5f);
  st[(size_t)btn * 640 + h * 64 + lane] = (_Float16)((t * r * g[lane] + b[lane]) * 0.8f);
}

// ---------------------------------------------------------------------------
// Temporal self-attention (verified R9): f16 qkvt input, fp32 LDS compute.
// ---------------------------------------------------------------------------
__global__ __launch_bounds__(256) void temporal_attn(
    const _Float16* __restrict__ qkvt, _Float16* __restrict__ st)
{
  __shared__ float qs[48][68];
  __shared__ float kt[48][68];
  __shared__ float vt[48][68];
  __shared__ float Ss[48][28];
  const int b = blockIdx.x / NN;
  const int n = blockIdx.x % NN;
  const int tid = threadIdx.x;
  const int lane = tid & 63;
  const int wave = tid >> 6;

  for (int idx = tid; idx < 48 * 16; idx += 256) {
    int row = idx >> 4, dq = (idx & 15) * 4;
    int h = row / 24, t = row - h * 24;
    const _Float16* g = qkvt + ((size_t)(b * TT + t) * NN + n) * 640 + h * 64 + dq;
    f16x4 a = *(const f16x4*)(g);
    f16x4 k = *(const f16x4*)(g + 128);
    f16x4 v = *(const f16x4*)(g + 256);
    float4 fa = {(float)a.x, (float)a.y, (float)a.z, (float)a.w};
    float4 fk = {(float)k.x, (float)k.y, (float)k.z, (float)k.w};
    float4 fv = {(float)v.x, (float)v.y, (float)v.z, (float)v.w};
    *(float4*)&qs[row][dq] = fa;
    *(float4*)&kt[row][dq] = fk;
    *(float4*)&vt[row][dq] = fv;
  }
  __syncthreads();

  for (int idx = tid; idx < 48 * 24; idx += 256) {
    int row = idx / 24, s = idx - row * 24;
    int krow = (row >= 24 ? 24 : 0) + s;
    float a0 = 0.f, a1 = 0.f, a2 = 0.f, a3 = 0.f;
    #pragma unroll
    for (int dq = 0; dq < 64; dq += 4) {
      float4 q = *(const float4*)&qs[row][dq];
      float4 k = *(const float4*)&kt[krow][dq];
      a0 = fmaf(q.x, k.x, a0);
      a1 = fmaf(q.y, k.y, a1);
      a2 = fmaf(q.z, k.z, a2);
      a3 = fmaf(q.w, k.w, a3);
    }
    Ss[row][s] = ((a0 + a1) + (a2 + a3)) * 0.125f;
  }
  __syncthreads();

  for (int r = wave; r < 48; r += 4) {
    float v = lane < 24 ? Ss[r][lane] : -1e30f;
    float mx = wred_max(v);
    float p = lane < 24 ? __expf(v - mx) : 0.f;
    float inv = 1.f / wred_sum(p);
    if (lane < 24) Ss[r][lane] = p * inv;
  }
  __syncthreads();

  for (int idx = tid; idx < 48 * 16; idx += 256) {
    int row = idx >> 4, dq = (idx & 15) * 4;
    int h = row / 24, t = row - h * 24;
    int bs = h * 24;
    float ax = 0.f, ay = 0.f, az = 0.f, aw = 0.f;
    #pragma unroll
    for (int s = 0; s < 24; ++s) {
      float p = Ss[row][s];
      float4 v = *(const float4*)&vt[bs + s][dq];
      ax = fmaf(p, v.x, ax);
      ay = fmaf(p, v.y, ay);
      az = fmaf(p, v.z, az);
      aw = fmaf(p, v.w, aw);
    }
    union { h2 h[2]; f16x4 v; } o2;
    o2.h[0] = __builtin_amdgcn_cvt_pkrtz(ax, ay);
    o2.h[1] = __builtin_amdgcn_cvt_pkrtz(az, aw);
    *(f16x4*)(st + ((size_t)(b * TT + t) * NN + n) * 640 + 384 + h * 64 + dq) = o2.v;
  }
}

// ---------------------------------------------------------------------------
// Temporal-global attention (verified R9): f16 qkvt input.
// ---------------------------------------------------------------------------
__global__ __launch_bounds__(256) void tglobal_attn(
    const _Float16* __restrict__ qkvt, const float* __restrict__ q_agg,
    const float* __restrict__ tmp_map, _Float16* __restrict__ st)
{
  __shared__ float qg[24][68];
  __shared__ float kg[48][68];
  __shared__ float vg[48][68];
  __shared__ float Sg[24][28];
  __shared__ float tgx[12][128];
  const int b = blockIdx.x / NN;
  const int n = blockIdx.x % NN;
  const int tid = threadIdx.x;
  const int lane = tid & 63;
  const int wave = tid >> 6;

  for (int idx = tid; idx < 48 * 16; idx += 256) {
    int row = idx >> 4, dq = (idx & 15) * 4;
    int h = row / 24, t = row - h * 24;
    const _Float16* g = qkvt + ((size_t)(b * TT + t) * NN + n) * 640 + 384 + h * 64 + dq;
    f16x4 k = *(const f16x4*)(g);
    f16x4 v = *(const f16x4*)(g + 128);
    float4 fk = {(float)k.x, (float)k.y, (float)k.z, (float)k.w};
    float4 fv = {(float)v.x, (float)v.y, (float)v.z, (float)v.w};
    *(float4*)&kg[row][dq] = fk;
    *(float4*)&vg[row][dq] = fv;
  }
  for (int idx = tid; idx < 24 * 16; idx += 256) {
    int row = idx >> 4, dq = (idx & 15) * 4;   // row = h*12+s
    int h = row / 12, s = row - h * 12;
    *(float4*)&qg[row][dq] =
        *(const float4*)(q_agg + ((size_t)n * 12 + s) * 128 + h * 64 + dq);
  }
  __syncthreads();

  for (int idx = tid; idx < 24 * 24; idx += 256) {
    int row = idx / 24, t = idx - row * 24;
    int krow = (row >= 12 ? 24 : 0) + t;
    float a0 = 0.f, a1 = 0.f, a2 = 0.f, a3 = 0.f;
    #pragma unroll
    for (int dq = 0; dq < 64; dq += 4) {
      float4 q = *(const float4*)&qg[row][dq];
      float4 k = *(const float4*)&kg[krow][dq];
      a0 = fmaf(q.x, k.x, a0);
      a1 = fmaf(q.y, k.y, a1);
      a2 = fmaf(q.z, k.z, a2);
      a3 = fmaf(q.w, k.w, a3);
    }
    Sg[row][t] = ((a0 + a1) + (a2 + a3)) * 0.125f;
  }
  __syncthreads();

  for (int r = wave; r < 24; r += 4) {
    float v = lane < 24 ? Sg[r][lane] : -1e30f;
    float mx = wred_max(v);
    float p = lane < 24 ? __expf(v - mx) : 0.f;
    float inv = 1.f / wred_sum(p);
    if (lane < 24) Sg[r][lane] = p * inv;
  }
  __syncthreads();

  for (int idx = tid; idx < 24 * 16; idx += 256) {
    int row = idx >> 4, dq = (idx & 15) * 4;   // row = h*12+s
    int h = row / 12, s = row - h * 12;
    int bt_ = h * 24;
    float ax = 0.f, ay = 0.f, az = 0.f, aw = 0.f;
    #pragma unroll
    for (int t = 0; t < 24; ++t) {
      float p = Sg[row][t];
      float4 v = *(const float4*)&vg[bt_ + t][dq];
      ax = fmaf(p, v.x, ax);
      ay = fmaf(p, v.y, ay);
      az = fmaf(p, v.z, az);
      aw = fmaf(p, v.w, aw);
    }
    float4 o = {ax, ay, az, aw};
    *(float4*)&tgx[s][h * 64 + dq] = o;
  }
  __syncthreads();

  for (int idx = tid; idx < 24 * 32; idx += 256) {
    int t = idx >> 5, cq = (idx & 31) * 4;
    const float* tm = tmp_map + ((size_t)(b * NN + n) * TT + t) * 12;
    float ax = 0.f, ay = 0.f, az = 0.f, aw = 0.f;
    #pragma unroll
    for (int s = 0; s < 12; ++s) {
      float m = tm[s];
      float4 v = *(const float4*)&tgx[s][cq];
      ax = fmaf(m, v.x, ax);
      ay = fmaf(m, v.y, ay);
      az = fmaf(m, v.z, az);
      aw = fmaf(m, v.w, aw);
    }
    union { h2 h[2]; f16x4 v; } o2;
    o2.h[0] = __builtin_amdgcn_cvt_pkrtz(ax, ay);
    o2.h[1] = __builtin_amdgcn_cvt_pkrtz(az, aw);
    *(f16x4*)(st + ((size_t)(b * TT + t) * NN + n) * 640 + 512 + cq) = o2.v;
  }
}

// ---------------------------------------------------------------------------
// Agg attention v2 (verified R9): LDS flat phases.
// ---------------------------------------------------------------------------
__global__ __launch_bounds__(256) void agg_attn(
    const float* __restrict__ qkva, float* __restrict__ sx, int Ni, int lg)
{
  __shared__ float qa[64][68];
  __shared__ float ka[64][68];
  __shared__ float va[64][68];
  __shared__ float Ss[64][68];
  const int h = blockIdx.x & 1;
  const int bt = blockIdx.x >> 1;
  const int tid = threadIdx.x;
  const int lane = tid & 63;
  const int wave = tid >> 6;

  for (int idx = tid; idx < Ni * 16; idx += 256) {
    int m = idx >> 4, dq = (idx & 15) * 4;
    const float* r = qkva + (size_t)(bt * Ni + m) * 384 + h * 64 + dq;
    *(float4*)&qa[m][dq] = *(const float4*)(r);
    *(float4*)&ka[m][dq] = *(const float4*)(r + 128);
    *(float4*)&va[m][dq] = *(const float4*)(r + 256);
  }
  __syncthreads();

  for (int idx = tid; idx < Ni * Ni; idx += 256) {
    int n = idx >> lg, m = idx & (Ni - 1);
    float a0 = 0.f, a1 = 0.f, a2 = 0.f, a3 = 0.f;
    #pragma unroll
    for (int dq = 0; dq < 64; dq += 4) {
      float4 q = *(const float4*)&qa[n][dq];
      float4 k = *(const float4*)&ka[m][dq];
      a0 = fmaf(q.x, k.x, a0);
      a1 = fmaf(q.y, k.y, a1);
      a2 = fmaf(q.z, k.z, a2);
      a3 = fmaf(q.w, k.w, a3);
    }
    Ss[n][m] = ((a0 + a1) + (a2 + a3)) * 0.125f;
  }
  __syncthreads();

  for (int r = wave; r < Ni; r += 4) {
    float v = lane < Ni ? Ss[r][lane] : -1e30f;
    float mx = wred_max(v);
    float p = lane < Ni ? __expf(v - mx) : 0.f;
    float inv = 1.f / wred_sum(p);
    if (lane < Ni) Ss[r][lane] = p * inv;
  }
  __syncthreads();

  for (int idx = tid; idx < Ni * 16; idx += 256) {
    int n = idx >> 4, dq = (idx & 15) * 4;
    float ax = 0.f, ay = 0.f, az = 0.f, aw = 0.f;
    for (int m = 0; m < Ni; ++m) {
      float p = Ss[n][m];
      float4 v = *(const float4*)&va[m][dq];
      ax = fmaf(p, v.x, ax);
      ay = fmaf(p, v.y, ay);
      az = fmaf(p, v.z, az);
      aw = fmaf(p, v.w, aw);
    }
    float4 o = {ax, ay, az, aw};
    *(float4*)(sx + (size_t)(bt * Ni + n) * 128 + h * 64 + dq) = o;
  }
}

// ---------------------------------------------------------------------------
// mmap v3 (verified R7/R9): LDS-staged M + s, 8n x 4c register tile.
// ---------------------------------------------------------------------------
__global__ __launch_bounds__(256) void mmap_kernel(
    const float* __restrict__ sx0, const float* __restrict__ sx1,
    const float* __restrict__ M0, const float* __restrict__ M1,
    _Float16* __restrict__ sg)
{
  __shared__ float sS[96][128];
  __shared__ float Mc[96][88];
  const int bt = blockIdx.x;
  const int chunk = blockIdx.y;
  const int tid = threadIdx.x;
  const int nbase = chunk * 88;

  for (int idx = tid; idx < 96 * 32; idx += 256) {
    int m = idx >> 5, c4 = (idx & 31) * 4;
    float4 v = (m < 32)
        ? *(const float4*)(sx0 + ((size_t)(bt * 32 + m) * 128 + c4))
        : *(const float4*)(sx1 + ((size_t)(bt * 64 + (m - 32)) * 128 + c4));
    *(float4*)&sS[m][c4] = v;
  }
  for (int idx = tid; idx < 96 * 88; idx += 256) {
    int m = idx / 88, nl = idx - m * 88;
    int n = nbase + nl; if (n > NN - 1) n = NN - 1;
    Mc[m][nl] = (m < 32) ? M0[m * NN + n] : M1[(m - 32) * NN + n];
  }
  __syncthreads();

  for (int idx = tid; idx < 352; idx += 256) {
    const int n0 = (idx >> 5) * 8;
    const int c4 = (idx & 31) * 4;
    f32x4 acc[8];
    #pragma unroll
    for (int j = 0; j < 8; ++j) {
      acc[j].x = 0.f; acc[j].y = 0.f; acc[j].z = 0.f; acc[j].w = 0.f;
    }
    #pragma unroll 4
    for (int m = 0; m < 96; ++m) {
      float4 sv = *(const float4*)&sS[m][c4];
      float mj[8];
      *(float4*)&mj[0] = *(const float4*)&Mc[m][n0];
      *(float4*)&mj[4] = *(const float4*)&Mc[m][n0 + 4];
      #pragma unroll
      for (int j = 0; j < 8; ++j) {
        acc[j].x = fmaf(mj[j], sv.x, acc[j].x);
        acc[j].y = fmaf(mj[j], sv.y, acc[j].y);
        acc[j].z = fmaf(mj[j], sv.z, acc[j].z);
        acc[j].w = fmaf(mj[j], sv.w, acc[j].w);
      }
    }
    #pragma unroll
    for (int j = 0; j < 8; ++j) {
      int n = nbase + n0 + j;
      if (n < NN) {
        union { h2 h[2]; f16x4 v; } o;
        o.h[0] = __builtin_amdgcn_cvt_pkrtz(acc[j].x, acc[j].y);
        o.h[1] = __builtin_amdgcn_cvt_pkrtz(acc[j].z, acc[j].w);
        *(f16x4*)(sg + ((size_t)bt * NN + n) * 128 + c4) = o.v;
      }
    }
  }
}

// ---------------------------------------------------------------------------
extern "C" void kernel_launch(void* const* d_in, const int* in_sizes, int n_in,
                              void* d_out, int out_size, void* d_ws, size_t ws_size,
                              hipStream_t stream)
{
  const float* x       = (const float*)d_in[0];
  const float* agg_x0  = (const float*)d_in[1];
  const float* agg_x1  = (const float*)d_in[2];
  const float* tmp_map = (const float*)d_in[3];
  const float* Wq_s = (const float*)d_in[4];
  const float* Wk_s = (const float*)d_in[5];
  const float* Wv_s = (const float*)d_in[6];
  const float* lq1 = (const float*)d_in[7];
  const float* lk1 = (const float*)d_in[8];
  const float* lq2 = (const float*)d_in[9];
  const float* lk2 = (const float*)d_in[10];
  const float* ln_g = (const float*)d_in[11];
  const float* ln_b = (const float*)d_in[12];
  const float* Wq_a0 = (const float*)d_in[13];
  const float* Wk_a0 = (const float*)d_in[14];
  const float* Wv_a0 = (const float*)d_in[15];
  const float* Wq_a1 = (const float*)d_in[16];
  const float* Wk_a1 = (const float*)d_in[17];
  const float* Wv_a1 = (const float*)d_in[18];
  const float* M0   = (const float*)d_in[19];
  const float* M1   = (const float*)d_in[20];
  const float* Wagg = (const float*)d_in[21];
  const float* bagg = (const float*)d_in[22];
  const float* Wq_t = (const float*)d_in[23];
  const float* Wk_t = (const float*)d_in[24];
  const float* Wv_t = (const float*)d_in[25];
  const float* q_agg = (const float*)d_in[26];
  const float* Wk_tg = (const float*)d_in[27];
  const float* Wv_tg = (const float*)d_in[28];
  const float* Wout  = (const float*)d_in[29];
  const float* bout  = (const float*)d_in[30];
  float* ws  = (float*)d_ws;
  float* out = (float*)d_out;

  const size_t o_lam  = 1114112;
  const size_t o_A    = 1114128;
  const size_t o_qkvt = o_A + 38780928;
  const size_t o_B    = o_qkvt + 32317440;

  float* lamp  = ws + o_lam;
  _Float16* qkv_h  = (_Float16*)(ws + o_A);      // f16, dead after diff_attn
  _Float16* st_h   = (_Float16*)(ws + o_A);      // reuses o_A after diff_ln
  _Float16* qkvt_h = (_Float16*)(ws + o_qkvt);
  _Float16* x_h = (_Float16*)(ws + o_B);         // dead after qkvt GEMM
  _Float16* a1_h = (_Float16*)(ws + o_B);        // written by diff_attn (after x_h dead)
  float* qkva0 = ws + o_B;                       // after diff_ln
  float* qkva1 = qkva0 + 2359296;
  float* sx0   = qkva0 + 7077888;
  float* sx1   = qkva0 + 7864320;
  _Float16* sg_h = (_Float16*)(qkva0 + 9437184);
  _Float16* Wh  = (_Float16*)ws;                 // f16 weights in old W_all region

  hipLaunchKernelGGL(lam_kernel, dim3(1), dim3(64), 0, stream, lq1, lk1, lq2, lk2, lamp);

  // ---- one-shot fp32->f16 conversion: x + all h16-GEMM weights ----
  CvtSegs cs;
  cs.src[0] = x;      cs.dst[0] = x_h;          cs.cnt8[0] = 25853952 / 8;
  cs.src[1] = Wq_s;   cs.dst[1] = Wh + 0;       cs.cnt8[1] = 131072 / 8;
  cs.src[2] = Wk_s;   cs.dst[2] = Wh + 131072;  cs.cnt8[2] = 131072 / 8;
  cs.src[3] = Wv_s;   cs.dst[3] = Wh + 262144;  cs.cnt8[3] = 131072 / 8;
  cs.src[4] = Wq_t;   cs.dst[4] = Wh + 393216;  cs.cnt8[4] = 65536 / 8;
  cs.src[5] = Wk_t;   cs.dst[5] = Wh + 458752;  cs.cnt8[5] = 65536 / 8;
  cs.src[6] = Wv_t;   cs.dst[6] = Wh + 524288;  cs.cnt8[6] = 65536 / 8;
  cs.src[7] = Wk_tg;  cs.dst[7] = Wh + 589824;  cs.cnt8[7] = 65536 / 8;
  cs.src[8] = Wv_tg;  cs.dst[8] = Wh + 655360;  cs.cnt8[8] = 65536 / 8;
  cs.src[9] = Wagg;   cs.dst[9] = Wh + 720896;  cs.cnt8[9] = 16384 / 8;
  cs.src[10] = Wout;  cs.dst[10] = Wh + 737280; cs.cnt8[10] = 327680 / 8;
  hipLaunchKernelGGL(cvt_f16, dim3(2048), dim3(256), 0, stream, cs, 11, 3364864);

  const int Mx = 50496;

  // qkv projection: N=768 (6 tiles), f16 out
  WSegsH wqkv; wqkv.p[0] = Wh; wqkv.p[1] = Wh + 65536;
  wqkv.p[2] = Wh + 131072; wqkv.p[3] = Wh + 196608;
  wqkv.p[4] = Wh + 262144; wqkv.p[5] = Wh + 327680;
  hipLaunchKernelGGL((gemm_h16<1>), dim3(395 * 6), dim3(256), 0, stream,
                     x_h, wqkv, (const float*)nullptr, (void*)qkv_h, Mx, 6, 512, 768);

  // temporal qkv: N=640 (5 tiles), f16 out — before diff_attn so x_h dies first
  WSegsH wt; wt.p[0] = Wh + 393216; wt.p[1] = Wh + 458752; wt.p[2] = Wh + 524288;
  wt.p[3] = Wh + 589824; wt.p[4] = Wh + 655360; wt.p[5] = Wh + 393216;
  hipLaunchKernelGGL((gemm_h16<1>), dim3(395 * 5), dim3(256), 0, stream,
                     x_h, wt, (const float*)nullptr, (void*)qkvt_h, Mx, 5, 512, 640);

  hipLaunchKernelGGL(diff_attn, dim3(768), dim3(512), 0, stream, qkv_h, a1_h);
  hipLaunchKernelGGL(diff_ln, dim3(Mx), dim3(256), 0, stream,
                     a1_h, a1_h + 12926976, lamp, ln_g, ln_b, st_h);
  hipLaunchKernelGGL(temporal_attn, dim3(8 * NN), dim3(256), 0, stream, qkvt_h, st_h);
  hipLaunchKernelGGL(tglobal_attn, dim3(8 * NN), dim3(256), 0, stream, qkvt_h, q_agg, tmp_map, st_h);

  // agg projections (small): legacy fp32 GEMM
  WSegs wa0; wa0.p[0] = Wq_a0; wa0.p[1] = Wk_a0; wa0.p[2] = Wv_a0;
  wa0.p[3] = wa0.p[4] = wa0.p[5] = Wq_a0;
  hipLaunchKernelGGL(gemm_nt_mfma, dim3(48 * 3), dim3(256), 0, stream,
                     agg_x0, wa0, (const float*)nullptr, qkva0, 6144, 3, 512, 384);
  WSegs wa1; wa1.p[0] = Wq_a1; wa1.p[1] = Wk_a1; wa1.p[2] = Wv_a1;
  wa1.p[3] = wa1.p[4] = wa1.p[5] = Wq_a1;
  hipLaunchKernelGGL(gemm_nt_mfma, dim3(96 * 3), dim3(256), 0, stream,
                     agg_x1, wa1, (const float*)nullptr, qkva1, 12288, 3, 512, 384);

  hipLaunchKernelGGL(agg_attn, dim3(384), dim3(256), 0, stream, qkva0, sx0, 32, 5);
  hipLaunchKernelGGL(agg_attn, dim3(384), dim3(256), 0, stream, qkva1, sx1, 64, 6);
  hipLaunchKernelGGL(mmap_kernel, dim3(192, 3), dim3(256), 0, stream, sx0, sx1, M0, M1, sg_h);

  // sg @ Wagg.T + bagg -> st_h cols 256..383 (f16 out)
  WSegsH wag; wag.p[0] = Wh + 720896;
  wag.p[1] = wag.p[2] = wag.p[3] = wag.p[4] = wag.p[5] = wag.p[0];
  hipLaunchKernelGGL((gemm_h16<1>), dim3(395 * 1), dim3(256), 0, stream,
                     sg_h, wag, bagg, (void*)(st_h + 256), Mx, 1, 128, 640);

  // out projection: N=512 (4 tiles of Wout), fp32 out
  WSegsH wo; wo.p[0] = Wh + 737280; wo.p[1] = Wh + 737280 + 81920;
  wo.p[2] = Wh + 737280 + 163840; wo.p[3] = Wh + 737280 + 245760;
  wo.p[4] = wo.p[5] = wo.p[0];
  hipLaunchKernelGGL((gemm_h16<0>), dim3(395 * 4), dim3(256), 0, stream,
                     st_h, wo, bout, (void*)out, Mx, 4, 640, 512);
}

// Round 11
// 842.612 us; speedup vs baseline: 1.0637x; 1.0637x over previous
//
#include <hip/hip_runtime.h>

#define NN 263
#define TT 24

typedef __fp16 h2 __attribute__((ext_vector_type(2)));
typedef _Float16 f16x4 __attribute__((ext_vector_type(4)));
typedef _Float16 f16x8 __attribute__((ext_vector_type(8)));
typedef float f32x4 __attribute__((ext_vector_type(4)));

struct WSegs  { const float* p[6]; };      // fp32 weight tiles (legacy gemm)
struct WSegsH { const _Float16* p[6]; };   // f16 weight tiles
struct CvtSegs { const float* src[11]; _Float16* dst[11]; int cnt8[11]; };

static __device__ __forceinline__ float wred_sum(float v) {
  #pragma unroll
  for (int off = 32; off >= 1; off >>= 1) v += __shfl_xor(v, off, 64);
  return v;
}
static __device__ __forceinline__ float wred_max(float v) {
  #pragma unroll
  for (int off = 32; off >= 1; off >>= 1) v = fmaxf(v, __shfl_xor(v, off, 64));
  return v;
}

// ---------------------------------------------------------------------------
// Batched fp32 -> f16 convert (x + all weights), 8 elems/thread-iter.
// ---------------------------------------------------------------------------
__global__ __launch_bounds__(256) void cvt_f16(CvtSegs cs, int nseg, int total8)
{
  const int stride = gridDim.x * 256;
  for (int i = blockIdx.x * 256 + threadIdx.x; i < total8; i += stride) {
    int r = i, s = 0;
    while (s < nseg - 1 && r >= cs.cnt8[s]) { r -= cs.cnt8[s]; ++s; }
    const float* sp = cs.src[s] + (size_t)r * 8;
    float4 a = *(const float4*)sp;
    float4 b = *(const float4*)(sp + 4);
    union { h2 h[4]; f16x8 v; } u;
    u.h[0] = __builtin_amdgcn_cvt_pkrtz(a.x, a.y);
    u.h[1] = __builtin_amdgcn_cvt_pkrtz(a.z, a.w);
    u.h[2] = __builtin_amdgcn_cvt_pkrtz(b.x, b.y);
    u.h[3] = __builtin_amdgcn_cvt_pkrtz(b.z, b.w);
    *(f16x8*)(cs.dst[s] + (size_t)r * 8) = u.v;
  }
}

// ---------------------------------------------------------------------------
// f16-in MFMA NT GEMM (verified R6-R10): dbuf LDS, one barrier/K-step.
// OUT_MODE: 0 = fp32 (ldc), 1 = f16 (ldc), 2 = f16 head-slab permuted:
//   slab = 2*bn + wc, addr = Cp + slab*(50496*64) + gm*64 + col  (col<64).
// Mode 2 gives each (type,head) an exclusive dense [rows][64] slab so no
// 256B HBM sector is shared across blocks/XCDs (R10 theory: the interleaved
// [row][768] layout's 128B head-slices false-share sectors across XCDs ->
// ~2x fetch + ~3x write RMW in the attention consumer).
// ---------------------------------------------------------------------------
template<int OUT_MODE>
__global__ __launch_bounds__(256) void gemm_h16(
    const _Float16* __restrict__ A, WSegsH wsg, const float* __restrict__ bias,
    void* __restrict__ Cp, int M, int NT, int K, int ldc)
{
  __shared__ _Float16 As[2][128][40];
  __shared__ _Float16 Bs[2][128][40];
  const int tid  = threadIdx.x;
  const int lane = tid & 63;
  const int wave = tid >> 6;
  const int wr = wave >> 1, wc = wave & 1;

  const int nwg = gridDim.x;
  const int q8 = nwg >> 3, r8 = nwg & 7;
  const int xcd = blockIdx.x & 7, pos = blockIdx.x >> 3;
  const int logical = (xcd < r8 ? xcd * (q8 + 1) : r8 * (q8 + 1) + (xcd - r8) * q8) + pos;
  const int bm = (logical / NT) * 128;
  const int bn = logical - (logical / NT) * NT;
  const _Float16* __restrict__ W = wsg.p[bn];

  const int srow = tid >> 2;
  const int sch  = (tid & 3) * 8;
  const _Float16* aptr[2];
  const _Float16* bptr[2];
  #pragma unroll
  for (int l = 0; l < 2; ++l) {
    int gm = bm + srow + 64 * l; if (gm > M - 1) gm = M - 1;
    aptr[l] = A + (size_t)gm * K + sch;
    bptr[l] = W + (size_t)(srow + 64 * l) * K + sch;
  }

  f32x4 acc[4][4];
  #pragma unroll
  for (int i = 0; i < 4; ++i)
    #pragma unroll
    for (int j = 0; j < 4; ++j) {
      acc[i][j].x = 0.f; acc[i][j].y = 0.f; acc[i][j].z = 0.f; acc[i][j].w = 0.f;
    }

  const int fr = lane & 15;
  const int fk = (lane >> 4) * 8;

  f16x8 av[2], bv[2];
  av[0] = *(const f16x8*)aptr[0]; av[1] = *(const f16x8*)aptr[1];
  bv[0] = *(const f16x8*)bptr[0]; bv[1] = *(const f16x8*)bptr[1];

  int cur = 0;
  for (int k0 = 0; k0 < K; k0 += 32, cur ^= 1) {
    *(f16x8*)&As[cur][srow     ][sch] = av[0];
    *(f16x8*)&As[cur][srow + 64][sch] = av[1];
    *(f16x8*)&Bs[cur][srow     ][sch] = bv[0];
    *(f16x8*)&Bs[cur][srow + 64][sch] = bv[1];
    if (k0 + 32 < K) {
      av[0] = *(const f16x8*)(aptr[0] + k0 + 32);
      av[1] = *(const f16x8*)(aptr[1] + k0 + 32);
      bv[0] = *(const f16x8*)(bptr[0] + k0 + 32);
      bv[1] = *(const f16x8*)(bptr[1] + k0 + 32);
    }
    __syncthreads();

    f16x8 af[4], bf[4];
    #pragma unroll
    for (int mi = 0; mi < 4; ++mi)
      af[mi] = *(const f16x8*)&As[cur][wr * 64 + mi * 16 + fr][fk];
    #pragma unroll
    for (int ni = 0; ni < 4; ++ni)
      bf[ni] = *(const f16x8*)&Bs[cur][wc * 64 + ni * 16 + fr][fk];
    #pragma unroll
    for (int mi = 0; mi < 4; ++mi)
      #pragma unroll
      for (int ni = 0; ni < 4; ++ni)
        acc[mi][ni] = __builtin_amdgcn_mfma_f32_16x16x32_f16(
            af[mi], bf[ni], acc[mi][ni], 0, 0, 0);
  }

  #pragma unroll
  for (int mi = 0; mi < 4; ++mi) {
    int rb = bm + wr * 64 + mi * 16 + (lane >> 4) * 4;
    #pragma unroll
    for (int r = 0; r < 4; ++r) {
      int gm = rb + r;
      if (gm < M) {
        if (OUT_MODE == 2) {
          _Float16* sb = (_Float16*)Cp
              + (size_t)(bn * 2 + wc) * (50496ull * 64ull) + (size_t)gm * 64;
          #pragma unroll
          for (int ni = 0; ni < 4; ++ni)
            sb[ni * 16 + fr] = (_Float16)acc[mi][ni][r];
        } else if (OUT_MODE == 1) {
          int gn = bn * 128 + wc * 64 + fr;
          #pragma unroll
          for (int ni = 0; ni < 4; ++ni) {
            float v = acc[mi][ni][r];
            if (bias) v += bias[gn + ni * 16];
            ((_Float16*)Cp)[(size_t)gm * ldc + gn + ni * 16] = (_Float16)v;
          }
        } else {
          int gn = bn * 128 + wc * 64 + fr;
          #pragma unroll
          for (int ni = 0; ni < 4; ++ni) {
            float v = acc[mi][ni][r];
            if (bias) v += bias[gn + ni * 16];
            ((float*)Cp)[(size_t)gm * ldc + gn + ni * 16] = v;
          }
        }
      }
    }
  }
}

// ---------------------------------------------------------------------------
// Legacy fp32-in GEMM — small agg projections only.
// ---------------------------------------------------------------------------
__global__ __launch_bounds__(256) void gemm_nt_mfma(
    const float* __restrict__ A, WSegs ws, const float* __restrict__ bias,
    float* __restrict__ C, int M, int NT, int K, int ldc)
{
  __shared__ _Float16 As[128][40];
  __shared__ _Float16 Bs[128][40];
  const int tid  = threadIdx.x;
  const int lane = tid & 63;
  const int wave = tid >> 6;
  const int wr = wave >> 1, wc = wave & 1;

  const int nwg = gridDim.x;
  const int q8 = nwg >> 3, r8 = nwg & 7;
  const int xcd = blockIdx.x & 7, pos = blockIdx.x >> 3;
  const int logical = (xcd < r8 ? xcd * (q8 + 1) : r8 * (q8 + 1) + (xcd - r8) * q8) + pos;
  const int bm = (logical / NT) * 128;
  const int bn = logical - (logical / NT) * NT;
  const float* __restrict__ W = ws.p[bn];

  const int srow = tid >> 3;
  const int skq  = (tid & 7) * 4;
  const float* aptr[4];
  const float* bptr[4];
  #pragma unroll
  for (int l = 0; l < 4; ++l) {
    int gm = bm + srow + 32 * l; if (gm > M - 1) gm = M - 1;
    aptr[l] = A + (size_t)gm * K + skq;
    bptr[l] = W + (size_t)(srow + 32 * l) * K + skq;
  }

  f32x4 acc[4][4];
  #pragma unroll
  for (int i = 0; i < 4; ++i)
    #pragma unroll
    for (int j = 0; j < 4; ++j) {
      acc[i][j].x = 0.f; acc[i][j].y = 0.f; acc[i][j].z = 0.f; acc[i][j].w = 0.f;
    }

  const int fr = lane & 15;
  const int fk = (lane >> 4) * 8;

  float4 av[4], bv[4];
  #pragma unroll
  for (int l = 0; l < 4; ++l) {
    av[l] = *(const float4*)(aptr[l]);
    bv[l] = *(const float4*)(bptr[l]);
  }

  for (int k0 = 0; k0 < K; k0 += 32) {
    #pragma unroll
    for (int l = 0; l < 4; ++l) {
      f16x4 a4, b4;
      a4.x = (_Float16)av[l].x; a4.y = (_Float16)av[l].y;
      a4.z = (_Float16)av[l].z; a4.w = (_Float16)av[l].w;
      b4.x = (_Float16)bv[l].x; b4.y = (_Float16)bv[l].y;
      b4.z = (_Float16)bv[l].z; b4.w = (_Float16)bv[l].w;
      *(f16x4*)&As[srow + 32 * l][skq] = a4;
      *(f16x4*)&Bs[srow + 32 * l][skq] = b4;
    }
    __syncthreads();

    if (k0 + 32 < K) {
      #pragma unroll
      for (int l = 0; l < 4; ++l) {
        av[l] = *(const float4*)(aptr[l] + k0 + 32);
        bv[l] = *(const float4*)(bptr[l] + k0 + 32);
      }
    }

    f16x8 af[4], bf[4];
    #pragma unroll
    for (int mi = 0; mi < 4; ++mi)
      af[mi] = *(const f16x8*)&As[wr * 64 + mi * 16 + fr][fk];
    #pragma unroll
    for (int ni = 0; ni < 4; ++ni)
      bf[ni] = *(const f16x8*)&Bs[wc * 64 + ni * 16 + fr][fk];
    #pragma unroll
    for (int mi = 0; mi < 4; ++mi)
      #pragma unroll
      for (int ni = 0; ni < 4; ++ni)
        acc[mi][ni] = __builtin_amdgcn_mfma_f32_16x16x32_f16(
            af[mi], bf[ni], acc[mi][ni], 0, 0, 0);
    __syncthreads();
  }

  #pragma unroll
  for (int mi = 0; mi < 4; ++mi) {
    int rb = bm + wr * 64 + mi * 16 + (lane >> 4) * 4;
    #pragma unroll
    for (int r = 0; r < 4; ++r) {
      int gm = rb + r;
      if (gm < M) {
        int gn = bn * 128 + wc * 64 + fr;
        float* crow = C + (size_t)gm * ldc + gn;
        #pragma unroll
        for (int ni = 0; ni < 4; ++ni) {
          float v = acc[mi][ni][r];
          if (bias) v += bias[gn + ni * 16];
          crow[ni * 16] = v;
        }
      }
    }
  }
}

// ---------------------------------------------------------------------------
__global__ void lam_kernel(const float* __restrict__ lq1, const float* __restrict__ lk1,
                           const float* __restrict__ lq2, const float* __restrict__ lk2,
                           float* __restrict__ out) {
  int lane = threadIdx.x;
  float v1 = lane < 32 ? lq1[lane] * lk1[lane] : 0.f;
  float v2 = lane < 32 ? lq2[lane] * lk2[lane] : 0.f;
  v1 = wred_sum(v1);
  v2 = wred_sum(v2);
  if (lane == 0) out[0] = expf(v1) - expf(v2) + 0.2f;
}

// ---------------------------------------------------------------------------
// Differential self-attention, MFMA (R10: head-slab qkv input [slab][row][64]
// and slab a1 output [half*4+h][row][64] — every block touches exclusive
// dense ranges, no cross-XCD 256B-sector sharing. Compute identical to the
// verified R8 kernel; only address maps changed).
// ---------------------------------------------------------------------------
__global__ __launch_bounds__(512, 2) void diff_attn(
    const _Float16* __restrict__ qkv, _Float16* __restrict__ aout)
{
  __shared__ _Float16 Ks[2][272][40];   // [half][k-row][d(32)+pad8]
  __shared__ h2 Vt[64][148];            // Vt[d][kp] = (V[2kp][d], V[2kp+1][d])
  __shared__ h2 Pb[8][16][148];         // per-wave P: [qrow(16)][kp], pad zeroed

  const int h  = blockIdx.x & 3;
  const int bt = blockIdx.x >> 2;
  const int tid = threadIdx.x;
  const int lane = tid & 63;
  const int wave = tid >> 6;
  const int fr = lane & 15;
  const int kb = (lane >> 4) * 4;
  const size_t S = 50496ull * 64ull;
  const _Float16* qh = qkv + (size_t)h * S       + (size_t)bt * NN * 64;
  const _Float16* kh = qkv + (size_t)(4 + h) * S + (size_t)bt * NN * 64;
  const _Float16* vh = qkv + (size_t)(8 + h) * S + (size_t)bt * NN * 64;

  // ---- K staging: direct f16 16B copies from dense slab ----
  for (int idx = tid; idx < 272 * 8; idx += 512) {
    int row = idx >> 3, c = idx & 7;
    int sr = row < NN ? row : NN - 1;
    f16x8 kv = *(const f16x8*)(kh + (size_t)sr * 64 + c * 8);
    *(f16x8*)&Ks[c >> 2][row][(c & 3) * 8] = kv;
  }
  // ---- V staging: thread owns (d, 4 consecutive kp) -> one b128 write ----
  {
    const ushort* vb = (const ushort*)vh;
    for (int idx = tid; idx < 64 * 37; idx += 512) {
      int d = idx & 63, kp0 = (idx >> 6) * 4;
      union { ushort u[8]; f16x8 v; } w;
      #pragma unroll
      for (int i = 0; i < 4; ++i) {
        int kp = kp0 + i;
        ushort lo = 0, hi = 0;
        if (kp < 136) {
          int m0 = 2 * kp, m1 = 2 * kp + 1;
          if (m0 > NN - 1) m0 = NN - 1;
          if (m1 > NN - 1) m1 = NN - 1;
          lo = vb[(size_t)m0 * 64 + d];
          hi = vb[(size_t)m1 * 64 + d];
        }
        w.u[2 * i] = lo; w.u[2 * i + 1] = hi;
      }
      *(f16x8*)&Vt[d][kp0] = w.v;
    }
  }
  // zero this wave's P pad columns kp=136..147
  {
    h2 z; z.x = (__fp16)0.f; z.y = (__fp16)0.f;
    #pragma unroll
    for (int t = 0; t < 3; ++t) Pb[wave][fr][136 + (kb >> 2) * 3 + t] = z;
  }
  __syncthreads();

  const float scq = 0.17677669529663687f;  // 1/sqrt(32)

  for (int task = wave; task < 34; task += 8) {
    const int chunk = task >> 1;
    const int half  = task & 1;

    int qsrc = chunk * 16 + fr; if (qsrc > NN - 1) qsrc = NN - 1;
    f16x8 qf = *(const f16x8*)(qh + (size_t)qsrc * 64 + half * 32 + kb * 2);

    f32x4 s[17];
    #pragma unroll
    for (int mt = 0; mt < 17; ++mt) {
      f16x8 af = *(const f16x8*)&Ks[half][mt * 16 + fr][kb * 2];
      f32x4 z4 = {0.f, 0.f, 0.f, 0.f};
      s[mt] = __builtin_amdgcn_mfma_f32_16x16x32_f16(af, qf, z4, 0, 0, 0);
    }

    // softmax: 4 independent max/sum chains (depth 17), then 2 shfl each
    float mx4[4] = {-1e30f, -1e30f, -1e30f, -1e30f};
    #pragma unroll
    for (int mt = 0; mt < 17; ++mt)
      #pragma unroll
      for (int r = 0; r < 4; ++r) {
        float v = s[mt][r] * scq;
        if (mt * 16 + kb + r >= NN) v = -1e30f;
        s[mt][r] = v;
        mx4[r] = fmaxf(mx4[r], v);
      }
    float mx = fmaxf(fmaxf(mx4[0], mx4[1]), fmaxf(mx4[2], mx4[3]));
    mx = fmaxf(mx, __shfl_xor(mx, 16, 64));
    mx = fmaxf(mx, __shfl_xor(mx, 32, 64));
    float sm4[4] = {0.f, 0.f, 0.f, 0.f};
    #pragma unroll
    for (int mt = 0; mt < 17; ++mt)
      #pragma unroll
      for (int r = 0; r < 4; ++r) {
        float p = __expf(s[mt][r] - mx);
        s[mt][r] = p;
        sm4[r] += p;
      }
    float sum = (sm4[0] + sm4[1]) + (sm4[2] + sm4[3]);
    sum += __shfl_xor(sum, 16, 64);
    sum += __shfl_xor(sum, 32, 64);
    float inv = 1.f / sum;

    // write P as one b64 per mt: kp = 8*mt + (kb>>1)
    #pragma unroll
    for (int mt = 0; mt < 17; ++mt) {
      union { h2 h[2]; f16x4 v; } pw;
      pw.h[0] = __builtin_amdgcn_cvt_pkrtz(s[mt][0] * inv, s[mt][1] * inv);
      pw.h[1] = __builtin_amdgcn_cvt_pkrtz(s[mt][2] * inv, s[mt][3] * inv);
      *(f16x4*)&Pb[wave][fr][8 * mt + (kb >> 1)] = pw.v;
    }

    // PV: 9 K-steps of 32 (k padded to 288 with zero P / zero V)
    f32x4 o[4];
    #pragma unroll
    for (int nt = 0; nt < 4; ++nt) {
      o[nt].x = 0.f; o[nt].y = 0.f; o[nt].z = 0.f; o[nt].w = 0.f;
    }
    #pragma unroll
    for (int s9 = 0; s9 < 9; ++s9) {
      f16x8 pa = *(const f16x8*)&Pb[wave][fr][16 * s9 + kb];
      #pragma unroll
      for (int nt = 0; nt < 4; ++nt) {
        f16x8 vb2 = *(const f16x8*)&Vt[nt * 16 + fr][16 * s9 + kb];
        o[nt] = __builtin_amdgcn_mfma_f32_16x16x32_f16(pa, vb2, o[nt], 0, 0, 0);
      }
    }

    // output: a1 slab [half*4+h][row][64] — block-exclusive dense region
    _Float16* ab = aout + (size_t)(half * 4 + h) * S + (size_t)bt * NN * 64;
    #pragma unroll
    for (int r = 0; r < 4; ++r) {
      int qrow = chunk * 16 + kb + r;
      if (qrow < NN) {
        _Float16* op = ab + (size_t)qrow * 64;
        #pragma unroll
        for (int nt = 0; nt < 4; ++nt) op[nt * 16 + fr] = (_Float16)o[nt][r];
      }
    }
  }
}

// ---------------------------------------------------------------------------
// diff-LN: slab a1/a2 input ([h][row][64] per half), f16 out (st_h).
// ---------------------------------------------------------------------------
__global__ __launch_bounds__(256) void diff_ln(
    const _Float16* __restrict__ a1, const _Float16* __restrict__ a2,
    const float* __restrict__ lamp,
    const float* __restrict__ g, const float* __restrict__ b,
    _Float16* __restrict__ st)
{
  const int btn = blockIdx.x;
  const int lane = threadIdx.x & 63;
  const int h = threadIdx.x >> 6;
  const float lam = lamp[0];
  size_t off = ((size_t)h * 50496 + btn) * 64 + lane;
  float y = (float)a1[off] - lam * (float)a2[off];
  float mean = wred_sum(y) * (1.f / 64.f);
  float t = y - mean;
  float var = wred_sum(t * t) * (1.f / 64.f);
  float r = rsqrtf(var + 1e-5f);
  st[(size_t)btn * 640 + h * 64 + lane] = (_Float16)((t * r * g[lane] + b[lane]) * 0.8f);
}

// ---------------------------------------------------------------------------
// Temporal self-attention (verified R9): f16 qkvt input, fp32 LDS compute.
// ---------------------------------------------------------------------------
__global__ __launch_bounds__(256) void temporal_attn(
    const _Float16* __restrict__ qkvt, _Float16* __restrict__ st)
{
  __shared__ float qs[48][68];
  __shared__ float kt[48][68];
  __shared__ float vt[48][68];
  __shared__ float Ss[48][28];
  const int b = blockIdx.x / NN;
  const int n = blockIdx.x % NN;
  const int tid = threadIdx.x;
  const int lane = tid & 63;
  const int wave = tid >> 6;

  for (int idx = tid; idx < 48 * 16; idx += 256) {
    int row = idx >> 4, dq = (idx & 15) * 4;
    int h = row / 24, t = row - h * 24;
    const _Float16* g = qkvt + ((size_t)(b * TT + t) * NN + n) * 640 + h * 64 + dq;
    f16x4 a = *(const f16x4*)(g);
    f16x4 k = *(const f16x4*)(g + 128);
    f16x4 v = *(const f16x4*)(g + 256);
    float4 fa = {(float)a.x, (float)a.y, (float)a.z, (float)a.w};
    float4 fk = {(float)k.x, (float)k.y, (float)k.z, (float)k.w};
    float4 fv = {(float)v.x, (float)v.y, (float)v.z, (float)v.w};
    *(float4*)&qs[row][dq] = fa;
    *(float4*)&kt[row][dq] = fk;
    *(float4*)&vt[row][dq] = fv;
  }
  __syncthreads();

  for (int idx = tid; idx < 48 * 24; idx += 256) {
    int row = idx / 24, s = idx - row * 24;
    int krow = (row >= 24 ? 24 : 0) + s;
    float a0 = 0.f, a1 = 0.f, a2 = 0.f, a3 = 0.f;
    #pragma unroll
    for (int dq = 0; dq < 64; dq += 4) {
      float4 q = *(const float4*)&qs[row][dq];
      float4 k = *(const float4*)&kt[krow][dq];
      a0 = fmaf(q.x, k.x, a0);
      a1 = fmaf(q.y, k.y, a1);
      a2 = fmaf(q.z, k.z, a2);
      a3 = fmaf(q.w, k.w, a3);
    }
    Ss[row][s] = ((a0 + a1) + (a2 + a3)) * 0.125f;
  }
  __syncthreads();

  for (int r = wave; r < 48; r += 4) {
    float v = lane < 24 ? Ss[r][lane] : -1e30f;
    float mx = wred_max(v);
    float p = lane < 24 ? __expf(v - mx) : 0.f;
    float inv = 1.f / wred_sum(p);
    if (lane < 24) Ss[r][lane] = p * inv;
  }
  __syncthreads();

  for (int idx = tid; idx < 48 * 16; idx += 256) {
    int row = idx >> 4, dq = (idx & 15) * 4;
    int h = row / 24, t = row - h * 24;
    int bs = h * 24;
    float ax = 0.f, ay = 0.f, az = 0.f, aw = 0.f;
    #pragma unroll
    for (int s = 0; s < 24; ++s) {
      float p = Ss[row][s];
      float4 v = *(const float4*)&vt[bs + s][dq];
      ax = fmaf(p, v.x, ax);
      ay = fmaf(p, v.y, ay);
      az = fmaf(p, v.z, az);
      aw = fmaf(p, v.w, aw);
    }
    union { h2 h[2]; f16x4 v; } o2;
    o2.h[0] = __builtin_amdgcn_cvt_pkrtz(ax, ay);
    o2.h[1] = __builtin_amdgcn_cvt_pkrtz(az, aw);
    *(f16x4*)(st + ((size_t)(b * TT + t) * NN + n) * 640 + 384 + h * 64 + dq) = o2.v;
  }
}

// ---------------------------------------------------------------------------
// Temporal-global attention (verified R9): f16 qkvt input.
// ---------------------------------------------------------------------------
__global__ __launch_bounds__(256) void tglobal_attn(
    const _Float16* __restrict__ qkvt, const float* __restrict__ q_agg,
    const float* __restrict__ tmp_map, _Float16* __restrict__ st)
{
  __shared__ float qg[24][68];
  __shared__ float kg[48][68];
  __shared__ float vg[48][68];
  __shared__ float Sg[24][28];
  __shared__ float tgx[12][128];
  const int b = blockIdx.x / NN;
  const int n = blockIdx.x % NN;
  const int tid = threadIdx.x;
  const int lane = tid & 63;
  const int wave = tid >> 6;

  for (int idx = tid; idx < 48 * 16; idx += 256) {
    int row = idx >> 4, dq = (idx & 15) * 4;
    int h = row / 24, t = row - h * 24;
    const _Float16* g = qkvt + ((size_t)(b * TT + t) * NN + n) * 640 + 384 + h * 64 + dq;
    f16x4 k = *(const f16x4*)(g);
    f16x4 v = *(const f16x4*)(g + 128);
    float4 fk = {(float)k.x, (float)k.y, (float)k.z, (float)k.w};
    float4 fv = {(float)v.x, (float)v.y, (float)v.z, (float)v.w};
    *(float4*)&kg[row][dq] = fk;
    *(float4*)&vg[row][dq] = fv;
  }
  for (int idx = tid; idx < 24 * 16; idx += 256) {
    int row = idx >> 4, dq = (idx & 15) * 4;   // row = h*12+s
    int h = row / 12, s = row - h * 12;
    *(float4*)&qg[row][dq] =
        *(const float4*)(q_agg + ((size_t)n * 12 + s) * 128 + h * 64 + dq);
  }
  __syncthreads();

  for (int idx = tid; idx < 24 * 24; idx += 256) {
    int row = idx / 24, t = idx - row * 24;
    int krow = (row >= 12 ? 24 : 0) + t;
    float a0 = 0.f, a1 = 0.f, a2 = 0.f, a3 = 0.f;
    #pragma unroll
    for (int dq = 0; dq < 64; dq += 4) {
      float4 q = *(const float4*)&qg[row][dq];
      float4 k = *(const float4*)&kg[krow][dq];
      a0 = fmaf(q.x, k.x, a0);
      a1 = fmaf(q.y, k.y, a1);
      a2 = fmaf(q.z, k.z, a2);
      a3 = fmaf(q.w, k.w, a3);
    }
    Sg[row][t] = ((a0 + a1) + (a2 + a3)) * 0.125f;
  }
  __syncthreads();

  for (int r = wave; r < 24; r += 4) {
    float v = lane < 24 ? Sg[r][lane] : -1e30f;
    float mx = wred_max(v);
    float p = lane < 24 ? __expf(v - mx) : 0.f;
    float inv = 1.f / wred_sum(p);
    if (lane < 24) Sg[r][lane] = p * inv;
  }
  __syncthreads();

  for (int idx = tid; idx < 24 * 16; idx += 256) {
    int row = idx >> 4, dq = (idx & 15) * 4;   // row = h*12+s
    int h = row / 12, s = row - h * 12;
    int bt_ = h * 24;
    float ax = 0.f, ay = 0.f, az = 0.f, aw = 0.f;
    #pragma unroll
    for (int t = 0; t < 24; ++t) {
      float p = Sg[row][t];
      float4 v = *(const float4*)&vg[bt_ + t][dq];
      ax = fmaf(p, v.x, ax);
      ay = fmaf(p, v.y, ay);
      az = fmaf(p, v.z, az);
      aw = fmaf(p, v.w, aw);
    }
    float4 o = {ax, ay, az, aw};
    *(float4*)&tgx[s][h * 64 + dq] = o;
  }
  __syncthreads();

  for (int idx = tid; idx < 24 * 32; idx += 256) {
    int t = idx >> 5, cq = (idx & 31) * 4;
    const float* tm = tmp_map + ((size_t)(b * NN + n) * TT + t) * 12;
    float ax = 0.f, ay = 0.f, az = 0.f, aw = 0.f;
    #pragma unroll
    for (int s = 0; s < 12; ++s) {
      float m = tm[s];
      float4 v = *(const float4*)&tgx[s][cq];
      ax = fmaf(m, v.x, ax);
      ay = fmaf(m, v.y, ay);
      az = fmaf(m, v.z, az);
      aw = fmaf(m, v.w, aw);
    }
    union { h2 h[2]; f16x4 v; } o2;
    o2.h[0] = __builtin_amdgcn_cvt_pkrtz(ax, ay);
    o2.h[1] = __builtin_amdgcn_cvt_pkrtz(az, aw);
    *(f16x4*)(st + ((size_t)(b * TT + t) * NN + n) * 640 + 512 + cq) = o2.v;
  }
}

// ---------------------------------------------------------------------------
// Agg attention v2 (verified R9): LDS flat phases.
// ---------------------------------------------------------------------------
__global__ __launch_bounds__(256) void agg_attn(
    const float* __restrict__ qkva, float* __restrict__ sx, int Ni, int lg)
{
  __shared__ float qa[64][68];
  __shared__ float ka[64][68];
  __shared__ float va[64][68];
  __shared__ float Ss[64][68];
  const int h = blockIdx.x & 1;
  const int bt = blockIdx.x >> 1;
  const int tid = threadIdx.x;
  const int lane = tid & 63;
  const int wave = tid >> 6;

  for (int idx = tid; idx < Ni * 16; idx += 256) {
    int m = idx >> 4, dq = (idx & 15) * 4;
    const float* r = qkva + (size_t)(bt * Ni + m) * 384 + h * 64 + dq;
    *(float4*)&qa[m][dq] = *(const float4*)(r);
    *(float4*)&ka[m][dq] = *(const float4*)(r + 128);
    *(float4*)&va[m][dq] = *(const float4*)(r + 256);
  }
  __syncthreads();

  for (int idx = tid; idx < Ni * Ni; idx += 256) {
    int n = idx >> lg, m = idx & (Ni - 1);
    float a0 = 0.f, a1 = 0.f, a2 = 0.f, a3 = 0.f;
    #pragma unroll
    for (int dq = 0; dq < 64; dq += 4) {
      float4 q = *(const float4*)&qa[n][dq];
      float4 k = *(const float4*)&ka[m][dq];
      a0 = fmaf(q.x, k.x, a0);
      a1 = fmaf(q.y, k.y, a1);
      a2 = fmaf(q.z, k.z, a2);
      a3 = fmaf(q.w, k.w, a3);
    }
    Ss[n][m] = ((a0 + a1) + (a2 + a3)) * 0.125f;
  }
  __syncthreads();

  for (int r = wave; r < Ni; r += 4) {
    float v = lane < Ni ? Ss[r][lane] : -1e30f;
    float mx = wred_max(v);
    float p = lane < Ni ? __expf(v - mx) : 0.f;
    float inv = 1.f / wred_sum(p);
    if (lane < Ni) Ss[r][lane] = p * inv;
  }
  __syncthreads();

  for (int idx = tid; idx < Ni * 16; idx += 256) {
    int n = idx >> 4, dq = (idx & 15) * 4;
    float ax = 0.f, ay = 0.f, az = 0.f, aw = 0.f;
    for (int m = 0; m < Ni; ++m) {
      float p = Ss[n][m];
      float4 v = *(const float4*)&va[m][dq];
      ax = fmaf(p, v.x, ax);
      ay = fmaf(p, v.y, ay);
      az = fmaf(p, v.z, az);
      aw = fmaf(p, v.w, aw);
    }
    float4 o = {ax, ay, az, aw};
    *(float4*)(sx + (size_t)(bt * Ni + n) * 128 + h * 64 + dq) = o;
  }
}

// ---------------------------------------------------------------------------
// mmap v3 (verified R7/R9): LDS-staged M + s, 8n x 4c register tile.
// ---------------------------------------------------------------------------
__global__ __launch_bounds__(256) void mmap_kernel(
    const float* __restrict__ sx0, const float* __restrict__ sx1,
    const float* __restrict__ M0, const float* __restrict__ M1,
    _Float16* __restrict__ sg)
{
  __shared__ float sS[96][128];
  __shared__ float Mc[96][88];
  const int bt = blockIdx.x;
  const int chunk = blockIdx.y;
  const int tid = threadIdx.x;
  const int nbase = chunk * 88;

  for (int idx = tid; idx < 96 * 32; idx += 256) {
    int m = idx >> 5, c4 = (idx & 31) * 4;
    float4 v = (m < 32)
        ? *(const float4*)(sx0 + ((size_t)(bt * 32 + m) * 128 + c4))
        : *(const float4*)(sx1 + ((size_t)(bt * 64 + (m - 32)) * 128 + c4));
    *(float4*)&sS[m][c4] = v;
  }
  for (int idx = tid; idx < 96 * 88; idx += 256) {
    int m = idx / 88, nl = idx - m * 88;
    int n = nbase + nl; if (n > NN - 1) n = NN - 1;
    Mc[m][nl] = (m < 32) ? M0[m * NN + n] : M1[(m - 32) * NN + n];
  }
  __syncthreads();

  for (int idx = tid; idx < 352; idx += 256) {
    const int n0 = (idx >> 5) * 8;
    const int c4 = (idx & 31) * 4;
    f32x4 acc[8];
    #pragma unroll
    for (int j = 0; j < 8; ++j) {
      acc[j].x = 0.f; acc[j].y = 0.f; acc[j].z = 0.f; acc[j].w = 0.f;
    }
    #pragma unroll 4
    for (int m = 0; m < 96; ++m) {
      float4 sv = *(const float4*)&sS[m][c4];
      float mj[8];
      *(float4*)&mj[0] = *(const float4*)&Mc[m][n0];
      *(float4*)&mj[4] = *(const float4*)&Mc[m][n0 + 4];
      #pragma unroll
      for (int j = 0; j < 8; ++j) {
        acc[j].x = fmaf(mj[j], sv.x, acc[j].x);
        acc[j].y = fmaf(mj[j], sv.y, acc[j].y);
        acc[j].z = fmaf(mj[j], sv.z, acc[j].z);
        acc[j].w = fmaf(mj[j], sv.w, acc[j].w);
      }
    }
    #pragma unroll
    for (int j = 0; j < 8; ++j) {
      int n = nbase + n0 + j;
      if (n < NN) {
        union { h2 h[2]; f16x4 v; } o;
        o.h[0] = __builtin_amdgcn_cvt_pkrtz(acc[j].x, acc[j].y);
        o.h[1] = __builtin_amdgcn_cvt_pkrtz(acc[j].z, acc[j].w);
        *(f16x4*)(sg + ((size_t)bt * NN + n) * 128 + c4) = o.v;
      }
    }
  }
}

// ---------------------------------------------------------------------------
extern "C" void kernel_launch(void* const* d_in, const int* in_sizes, int n_in,
                              void* d_out, int out_size, void* d_ws, size_t ws_size,
                              hipStream_t stream)
{
  const float* x       = (const float*)d_in[0];
  const float* agg_x0  = (const float*)d_in[1];
  const float* agg_x1  = (const float*)d_in[2];
  const float* tmp_map = (const float*)d_in[3];
  const float* Wq_s = (const float*)d_in[4];
  const float* Wk_s = (const float*)d_in[5];
  const float* Wv_s = (const float*)d_in[6];
  const float* lq1 = (const float*)d_in[7];
  const float* lk1 = (const float*)d_in[8];
  const float* lq2 = (const float*)d_in[9];
  const float* lk2 = (const float*)d_in[10];
  const float* ln_g = (const float*)d_in[11];
  const float* ln_b = (const float*)d_in[12];
  const float* Wq_a0 = (const float*)d_in[13];
  const float* Wk_a0 = (const float*)d_in[14];
  const float* Wv_a0 = (const float*)d_in[15];
  const float* Wq_a1 = (const float*)d_in[16];
  const float* Wk_a1 = (const float*)d_in[17];
  const float* Wv_a1 = (const float*)d_in[18];
  const float* M0   = (const float*)d_in[19];
  const float* M1   = (const float*)d_in[20];
  const float* Wagg = (const float*)d_in[21];
  const float* bagg = (const float*)d_in[22];
  const float* Wq_t = (const float*)d_in[23];
  const float* Wk_t = (const float*)d_in[24];
  const float* Wv_t = (const float*)d_in[25];
  const float* q_agg = (const float*)d_in[26];
  const float* Wk_tg = (const float*)d_in[27];
  const float* Wv_tg = (const float*)d_in[28];
  const float* Wout  = (const float*)d_in[29];
  const float* bout  = (const float*)d_in[30];
  float* ws  = (float*)d_ws;
  float* out = (float*)d_out;

  const size_t o_lam  = 1114112;
  const size_t o_A    = 1114128;
  const size_t o_qkvt = o_A + 38780928;
  const size_t o_B    = o_qkvt + 32317440;

  float* lamp  = ws + o_lam;
  _Float16* qkv_h  = (_Float16*)(ws + o_A);      // 12 head-slabs, dead after diff_attn
  _Float16* st_h   = (_Float16*)(ws + o_A);      // reuses o_A after diff_ln
  _Float16* qkvt_h = (_Float16*)(ws + o_qkvt);
  _Float16* x_h = (_Float16*)(ws + o_B);         // dead after qkvt GEMM
  _Float16* a1_h = (_Float16*)(ws + o_B);        // 8 slabs, written by diff_attn
  float* qkva0 = ws + o_B;                       // after diff_ln
  float* qkva1 = qkva0 + 2359296;
  float* sx0   = qkva0 + 7077888;
  float* sx1   = qkva0 + 7864320;
  _Float16* sg_h = (_Float16*)(qkva0 + 9437184);
  _Float16* Wh  = (_Float16*)ws;                 // f16 weights in old W_all region

  hipLaunchKernelGGL(lam_kernel, dim3(1), dim3(64), 0, stream, lq1, lk1, lq2, lk2, lamp);

  // ---- one-shot fp32->f16 conversion: x + all h16-GEMM weights ----
  CvtSegs cs;
  cs.src[0] = x;      cs.dst[0] = x_h;          cs.cnt8[0] = 25853952 / 8;
  cs.src[1] = Wq_s;   cs.dst[1] = Wh + 0;       cs.cnt8[1] = 131072 / 8;
  cs.src[2] = Wk_s;   cs.dst[2] = Wh + 131072;  cs.cnt8[2] = 131072 / 8;
  cs.src[3] = Wv_s;   cs.dst[3] = Wh + 262144;  cs.cnt8[3] = 131072 / 8;
  cs.src[4] = Wq_t;   cs.dst[4] = Wh + 393216;  cs.cnt8[4] = 65536 / 8;
  cs.src[5] = Wk_t;   cs.dst[5] = Wh + 458752;  cs.cnt8[5] = 65536 / 8;
  cs.src[6] = Wv_t;   cs.dst[6] = Wh + 524288;  cs.cnt8[6] = 65536 / 8;
  cs.src[7] = Wk_tg;  cs.dst[7] = Wh + 589824;  cs.cnt8[7] = 65536 / 8;
  cs.src[8] = Wv_tg;  cs.dst[8] = Wh + 655360;  cs.cnt8[8] = 65536 / 8;
  cs.src[9] = Wagg;   cs.dst[9] = Wh + 720896;  cs.cnt8[9] = 16384 / 8;
  cs.src[10] = Wout;  cs.dst[10] = Wh + 737280; cs.cnt8[10] = 327680 / 8;
  hipLaunchKernelGGL(cvt_f16, dim3(2048), dim3(256), 0, stream, cs, 11, 3364864);

  const int Mx = 50496;

  // qkv projection: N=768 (6 tiles), head-slab f16 out (mode 2)
  WSegsH wqkv; wqkv.p[0] = Wh; wqkv.p[1] = Wh + 65536;
  wqkv.p[2] = Wh + 131072; wqkv.p[3] = Wh + 196608;
  wqkv.p[4] = Wh + 262144; wqkv.p[5] = Wh + 327680;
  hipLaunchKernelGGL((gemm_h16<2>), dim3(395 * 6), dim3(256), 0, stream,
                     x_h, wqkv, (const float*)nullptr, (void*)qkv_h, Mx, 6, 512, 768);

  // temporal qkv: N=640 (5 tiles), interleaved f16 out — before diff_attn
  WSegsH wt; wt.p[0] = Wh + 393216; wt.p[1] = Wh + 458752; wt.p[2] = Wh + 524288;
  wt.p[3] = Wh + 589824; wt.p[4] = Wh + 655360; wt.p[5] = Wh + 393216;
  hipLaunchKernelGGL((gemm_h16<1>), dim3(395 * 5), dim3(256), 0, stream,
                     x_h, wt, (const float*)nullptr, (void*)qkvt_h, Mx, 5, 512, 640);

  hipLaunchKernelGGL(diff_attn, dim3(768), dim3(512), 0, stream, qkv_h, a1_h);
  hipLaunchKernelGGL(diff_ln, dim3(Mx), dim3(256), 0, stream,
                     a1_h, a1_h + 12926976, lamp, ln_g, ln_b, st_h);
  hipLaunchKernelGGL(temporal_attn, dim3(8 * NN), dim3(256), 0, stream, qkvt_h, st_h);
  hipLaunchKernelGGL(tglobal_attn, dim3(8 * NN), dim3(256), 0, stream, qkvt_h, q_agg, tmp_map, st_h);

  // agg projections (small): legacy fp32 GEMM
  WSegs wa0; wa0.p[0] = Wq_a0; wa0.p[1] = Wk_a0; wa0.p[2] = Wv_a0;
  wa0.p[3] = wa0.p[4] = wa0.p[5] = Wq_a0;
  hipLaunchKernelGGL(gemm_nt_mfma, dim3(48 * 3), dim3(256), 0, stream,
                     agg_x0, wa0, (const float*)nullptr, qkva0, 6144, 3, 512, 384);
  WSegs wa1; wa1.p[0] = Wq_a1; wa1.p[1] = Wk_a1; wa1.p[2] = Wv_a1;
  wa1.p[3] = wa1.p[4] = wa1.p[5] = Wq_a1;
  hipLaunchKernelGGL(gemm_nt_mfma, dim3(96 * 3), dim3(256), 0, stream,
                     agg_x1, wa1, (const float*)nullptr, qkva1, 12288, 3, 512, 384);

  hipLaunchKernelGGL(agg_attn, dim3(384), dim3(256), 0, stream, qkva0, sx0, 32, 5);
  hipLaunchKernelGGL(agg_attn, dim3(384), dim3(256), 0, stream, qkva1, sx1, 64, 6);
  hipLaunchKernelGGL(mmap_kernel, dim3(192, 3), dim3(256), 0, stream, sx0, sx1, M0, M1, sg_h);

  // sg @ Wagg.T + bagg -> st_h cols 256..383 (f16 out, interleaved)
  WSegsH wag; wag.p[0] = Wh + 720896;
  wag.p[1] = wag.p[2] = wag.p[3] = wag.p[4] = wag.p[5] = wag.p[0];
  hipLaunchKernelGGL((gemm_h16<1>), dim3(395 * 1), dim3(256), 0, stream,
                     sg_h, wag, bagg, (void*)(st_h + 256), Mx, 1, 128, 640);

  // out projection: N=512 (4 tiles of Wout), fp32 out
  WSegsH wo; wo.p[0] = Wh + 737280; wo.p[1] = Wh + 737280 + 81920;
  wo.p[2] = Wh + 737280 + 163840; wo.p[3] = Wh + 737280 + 245760;
  wo.p[4] = wo.p[5] = wo.p[0];
  hipLaunchKernelGGL((gemm_h16<0>), dim3(395 * 4), dim3(256), 0, stream,
                     st_h, wo, bout, (void*)out, Mx, 4, 640, 512);
}